// Round 1
// baseline (569.090 us; speedup 1.0000x reference)
//
#include <hip/hip_runtime.h>
#include <math.h>

#define B_ 64
#define S_ 128
#define E_ 256
#define D_ 128
#define N_ 4096

// ---------------------------------------------------------------------------
// K1: epT[b][d][s] = sum_k e[b][s][k] * W[d][k] + bias[d]
// One workgroup per (b, d-quarter). K staged in LDS chunks of 64.
// Strides padded to 68 floats: W-read 2-way bank alias (free), e-read broadcast.
// ---------------------------------------------------------------------------
__global__ __launch_bounds__(256) void k1_ep(
    const float* __restrict__ e, const float* __restrict__ W,
    const float* __restrict__ bias, float* __restrict__ epT)
{
    __shared__ __align__(16) float el[128 * 68];
    __shared__ __align__(16) float Wl[32 * 68];
    const int t = threadIdx.x;
    const int b = blockIdx.x >> 2;
    const int d0 = (blockIdx.x & 3) << 5;
    const int d_loc = t & 15;   // thread owns d = d0 + d_loc + 16m, m<2
    const int s_loc = t >> 4;   // thread owns s = s_loc + 16u, u<8

    float acc[2][8];
#pragma unroll
    for (int m = 0; m < 2; ++m)
#pragma unroll
        for (int u = 0; u < 8; ++u) acc[m][u] = 0.f;

    for (int kc = 0; kc < E_; kc += 64) {
        for (int i = t; i < 2048; i += 256) {           // e[b][:, kc:kc+64]
            const int r = i >> 4, c4 = (i & 15) << 2;
            *(float4*)(el + r * 68 + c4) =
                *(const float4*)(e + (b * S_ + r) * E_ + kc + c4);
        }
        for (int i = t; i < 512; i += 256) {            // W[d0:d0+32, kc:kc+64]
            const int r = i >> 4, c4 = (i & 15) << 2;
            *(float4*)(Wl + r * 68 + c4) =
                *(const float4*)(W + (d0 + r) * E_ + kc + c4);
        }
        __syncthreads();
#pragma unroll 4
        for (int kk = 0; kk < 64; kk += 4) {
            const float4 w0 = *(const float4*)(Wl + d_loc * 68 + kk);
            const float4 w1 = *(const float4*)(Wl + (d_loc + 16) * 68 + kk);
#pragma unroll
            for (int u = 0; u < 8; ++u) {
                const float4 ev = *(const float4*)(el + (s_loc + 16 * u) * 68 + kk);
                acc[0][u] += w0.x * ev.x + w0.y * ev.y + w0.z * ev.z + w0.w * ev.w;
                acc[1][u] += w1.x * ev.x + w1.y * ev.y + w1.z * ev.z + w1.w * ev.w;
            }
        }
        __syncthreads();
    }
#pragma unroll
    for (int m = 0; m < 2; ++m) {
        const int dg = d0 + d_loc + 16 * m;
        const float bz = bias[dg];
#pragma unroll
        for (int u = 0; u < 8; ++u)
            epT[(b * D_ + dg) * S_ + s_loc + 16 * u] = acc[m][u] + bz;
    }
}

__device__ __forceinline__ float4 exp4(float4 v, float mx) {
    return make_float4(expf(v.x - mx), expf(v.y - mx),
                       expf(v.z - mx), expf(v.w - mx));
}

// ---------------------------------------------------------------------------
// K2: fused scores -> softmax(S) -> context, one WG per (b, 32-col n-tile).
// LDS: bufEp 18.0KB (ep chunks, two layouts) + hT 16KB (h tile, reused as c
// tile) + sT 16.5KB (scores^T/beta^T) = 51.7KB -> 3 blocks/CU.
// ---------------------------------------------------------------------------
__global__ __launch_bounds__(256) void k2_attn(
    const float* __restrict__ h, const float* __restrict__ epT,
    float* __restrict__ out)
{
    __shared__ __align__(16) float bufEp[4608];   // ph1: [32][132], ph2: [128][36]
    __shared__ __align__(16) float hT[128 * 32];  // h tile; later c tile
    __shared__ __align__(16) float sT[32 * 132];  // scores^T -> beta^T
    const int t = threadIdx.x;
    const int b = blockIdx.x >> 7;
    const int n0 = (blockIdx.x & 127) << 5;

    for (int i = t; i < 1024; i += 256) {         // stage h[b][:, n0:n0+32]
        const int r = i >> 3, c4 = (i & 7) << 2;
        *(float4*)(hT + r * 32 + c4) =
            *(const float4*)(h + (b * D_ + r) * N_ + n0 + c4);
    }
    __syncthreads();

    // Phase 1: scores s[s][j] = sum_d epT[d][s] * hT[d][j], outer-product form.
    const int s4 = (t & 31) << 2;   // 4 contiguous s
    const int j4 = (t >> 5) << 2;   // 4 contiguous j
    float acc[4][4];
#pragma unroll
    for (int i = 0; i < 4; ++i)
#pragma unroll
        for (int k = 0; k < 4; ++k) acc[i][k] = 0.f;

    for (int dc = 0; dc < D_; dc += 32) {
        for (int i = t; i < 1024; i += 256) {     // stage epT rows dc..dc+31
            const int r = i >> 5, c4 = (i & 31) << 2;
            *(float4*)(bufEp + r * 132 + c4) =
                *(const float4*)(epT + (b * D_ + dc + r) * S_ + c4);
        }
        __syncthreads();
#pragma unroll 8
        for (int dd = 0; dd < 32; ++dd) {
            const float4 a = *(const float4*)(bufEp + dd * 132 + s4);
            const float4 v = *(const float4*)(hT + (dc + dd) * 32 + j4);
            acc[0][0] += a.x * v.x; acc[0][1] += a.x * v.y; acc[0][2] += a.x * v.z; acc[0][3] += a.x * v.w;
            acc[1][0] += a.y * v.x; acc[1][1] += a.y * v.y; acc[1][2] += a.y * v.z; acc[1][3] += a.y * v.w;
            acc[2][0] += a.z * v.x; acc[2][1] += a.z * v.y; acc[2][2] += a.z * v.z; acc[2][3] += a.z * v.w;
            acc[3][0] += a.w * v.x; acc[3][1] += a.w * v.y; acc[3][2] += a.w * v.z; acc[3][3] += a.w * v.w;
        }
        __syncthreads();
    }
#pragma unroll
    for (int k = 0; k < 4; ++k)                   // transpose-write: sT[j][s]
        *(float4*)(sT + (j4 + k) * 132 + s4) =
            make_float4(acc[0][k], acc[1][k], acc[2][k], acc[3][k]);
    __syncthreads();

    // Softmax over s (each sT row). 8 lanes per row, shuffle-reduce.
    {
        const int j = t >> 3, q = t & 7;
        float* row = sT + j * 132 + (q << 4);
        float4 v0 = *(float4*)(row);
        float4 v1 = *(float4*)(row + 4);
        float4 v2 = *(float4*)(row + 8);
        float4 v3 = *(float4*)(row + 12);
        float mx = fmaxf(fmaxf(fmaxf(v0.x, v0.y), fmaxf(v0.z, v0.w)),
                         fmaxf(fmaxf(v1.x, v1.y), fmaxf(v1.z, v1.w)));
        mx = fmaxf(mx, fmaxf(fmaxf(fmaxf(v2.x, v2.y), fmaxf(v2.z, v2.w)),
                             fmaxf(fmaxf(v3.x, v3.y), fmaxf(v3.z, v3.w))));
#pragma unroll
        for (int off = 1; off < 8; off <<= 1) mx = fmaxf(mx, __shfl_xor(mx, off));
        v0 = exp4(v0, mx); v1 = exp4(v1, mx); v2 = exp4(v2, mx); v3 = exp4(v3, mx);
        float sm = (v0.x + v0.y + v0.z + v0.w) + (v1.x + v1.y + v1.z + v1.w)
                 + (v2.x + v2.y + v2.z + v2.w) + (v3.x + v3.y + v3.z + v3.w);
#pragma unroll
        for (int off = 1; off < 8; off <<= 1) sm += __shfl_xor(sm, off);
        const float inv = 1.0f / sm;
        v0.x *= inv; v0.y *= inv; v0.z *= inv; v0.w *= inv;
        v1.x *= inv; v1.y *= inv; v1.z *= inv; v1.w *= inv;
        v2.x *= inv; v2.y *= inv; v2.z *= inv; v2.w *= inv;
        v3.x *= inv; v3.y *= inv; v3.z *= inv; v3.w *= inv;
        *(float4*)(row) = v0; *(float4*)(row + 4) = v1;
        *(float4*)(row + 8) = v2; *(float4*)(row + 12) = v3;
    }
    __syncthreads();

    // Phase 2: c[d][j] = sum_s epT[d][s] * beta[s][j], inner-product form.
    // Strided ownership d in {dt+32m}, j in {jt+8r} -> conflict-free b128 reads.
    const int dt = t >> 3;   // 0..31
    const int jt = t & 7;    // 0..7
    float acc2[4][4];
#pragma unroll
    for (int m = 0; m < 4; ++m)
#pragma unroll
        for (int r = 0; r < 4; ++r) acc2[m][r] = 0.f;

    for (int sc = 0; sc < S_; sc += 32) {
        for (int i = t; i < 1024; i += 256) {     // stage epT[:, sc:sc+32]
            const int r = i >> 3, c4 = (i & 7) << 2;
            *(float4*)(bufEp + r * 36 + c4) =
                *(const float4*)(epT + (b * D_ + r) * S_ + sc + c4);
        }
        __syncthreads();
#pragma unroll
        for (int ss = 0; ss < 32; ss += 4) {
            float4 av[4], bv[4];
#pragma unroll
            for (int m = 0; m < 4; ++m)
                av[m] = *(const float4*)(bufEp + (dt + 32 * m) * 36 + ss);
#pragma unroll
            for (int r = 0; r < 4; ++r)
                bv[r] = *(const float4*)(sT + (jt + 8 * r) * 132 + sc + ss);
#pragma unroll
            for (int m = 0; m < 4; ++m)
#pragma unroll
                for (int r = 0; r < 4; ++r)
                    acc2[m][r] += av[m].x * bv[r].x + av[m].y * bv[r].y
                                + av[m].z * bv[r].z + av[m].w * bv[r].w;
        }
        __syncthreads();
    }

#pragma unroll
    for (int m = 0; m < 4; ++m)                   // c tile into LDS (reuse hT)
#pragma unroll
        for (int r = 0; r < 4; ++r)
            hT[(dt + 32 * m) * 32 + jt + 8 * r] = acc2[m][r];
    __syncthreads();

    for (int i = t; i < 1024; i += 256) {         // coalesced float4 store
        const int r = i >> 3, c4 = (i & 7) << 2;
        *(float4*)(out + (b * D_ + r) * N_ + n0 + c4) = *(float4*)(hT + r * 32 + c4);
    }
}

extern "C" void kernel_launch(void* const* d_in, const int* in_sizes, int n_in,
                              void* d_out, int out_size, void* d_ws, size_t ws_size,
                              hipStream_t stream) {
    const float* e    = (const float*)d_in[0];
    const float* h    = (const float*)d_in[1];
    const float* W    = (const float*)d_in[2];
    const float* bias = (const float*)d_in[3];
    float* out = (float*)d_out;
    float* epT = (float*)d_ws;   // B*D*S floats = 4 MB scratch

    hipLaunchKernelGGL(k1_ep, dim3(B_ * 4), dim3(256), 0, stream, e, W, bias, epT);
    hipLaunchKernelGGL(k2_attn, dim3(B_ * 128), dim3(256), 0, stream, h, epT, out);
}

// Round 3
// 302.098 us; speedup vs baseline: 1.8838x; 1.8838x over previous
//
#include <hip/hip_runtime.h>
#include <math.h>

#define B_ 64
#define S_ 128
#define E_ 256
#define D_ 128
#define N_ 4096

typedef _Float16 f16;
typedef _Float16 f16x8 __attribute__((ext_vector_type(8)));
typedef float f32x4 __attribute__((ext_vector_type(4)));

__device__ __forceinline__ unsigned pack2(f16 a, f16 b) {
    union { f16 h[2]; unsigned u; } x;
    x.h[0] = a; x.h[1] = b; return x.u;
}

__device__ __forceinline__ f32x4 mfma16(f16x8 a, f16x8 b, f32x4 c) {
    return __builtin_amdgcn_mfma_f32_16x16x32_f16(a, b, c, 0, 0, 0);
}

// ---------------------------------------------------------------------------
// K1: ep = e*W^T + b, emitted as f16 hi/lo splits in two layouts:
//   epA_h/epA_l: [b][s][d] halves (phase-1 A fragments, d-contiguous)
//   epT_h:       [b][d][s] halves (phase-2 A fragments, s-contiguous)
// 512 WGs (b x d-quarter x s-half). Thread owns d = d0+2p+m, s = s0+2q+v+32u.
// (Round-2 bug: u-stride was 16 -> rows 48..63 never computed. Fixed: 32.)
// ---------------------------------------------------------------------------
__global__ __launch_bounds__(256) void k1_ep(
    const float* __restrict__ e, const float* __restrict__ W,
    const float* __restrict__ bias,
    unsigned* __restrict__ epA_h, unsigned* __restrict__ epA_l,
    unsigned* __restrict__ epT_h)
{
    __shared__ __align__(16) float el[64 * 68];
    __shared__ __align__(16) float Wl[32 * 68];
    const int t = threadIdx.x;
    const int b  = blockIdx.x >> 3;
    const int d0 = ((blockIdx.x >> 1) & 3) << 5;
    const int s0 = (blockIdx.x & 1) << 6;
    const int p = t & 15;   // d = d0 + 2p + m
    const int q = t >> 4;   // s = s0 + 2q + v + 32u

    float acc[2][2][2];
#pragma unroll
    for (int m = 0; m < 2; ++m)
#pragma unroll
        for (int u = 0; u < 2; ++u)
            acc[m][u][0] = acc[m][u][1] = 0.f;

    for (int kc = 0; kc < E_; kc += 64) {
#pragma unroll
        for (int it = 0; it < 4; ++it) {            // e[b][s0..s0+64, kc..kc+64]
            const int lin = it * 256 + t;
            const int r = lin >> 4, c4 = (lin & 15) << 2;
            *(float4*)(el + r * 68 + c4) =
                *(const float4*)(e + (b * S_ + s0 + r) * E_ + kc + c4);
        }
#pragma unroll
        for (int it = 0; it < 2; ++it) {            // W[d0..d0+32, kc..kc+64]
            const int lin = it * 256 + t;
            const int r = lin >> 4, c4 = (lin & 15) << 2;
            *(float4*)(Wl + r * 68 + c4) =
                *(const float4*)(W + (d0 + r) * E_ + kc + c4);
        }
        __syncthreads();
#pragma unroll 4
        for (int kk = 0; kk < 64; kk += 4) {
            const float4 w0 = *(const float4*)(Wl + (2 * p) * 68 + kk);
            const float4 w1 = *(const float4*)(Wl + (2 * p + 1) * 68 + kk);
#pragma unroll
            for (int u = 0; u < 2; ++u) {
                const float4 e0 = *(const float4*)(el + (2 * q + 32 * u) * 68 + kk);
                const float4 e1 = *(const float4*)(el + (2 * q + 1 + 32 * u) * 68 + kk);
                acc[0][u][0] += w0.x * e0.x + w0.y * e0.y + w0.z * e0.z + w0.w * e0.w;
                acc[0][u][1] += w0.x * e1.x + w0.y * e1.y + w0.z * e1.z + w0.w * e1.w;
                acc[1][u][0] += w1.x * e0.x + w1.y * e0.y + w1.z * e0.z + w1.w * e0.w;
                acc[1][u][1] += w1.x * e1.x + w1.y * e1.y + w1.z * e1.z + w1.w * e1.w;
            }
        }
        __syncthreads();
    }

    const float bz[2] = { bias[d0 + 2 * p], bias[d0 + 2 * p + 1] };
    f16 hi[2][2][2], lo[2][2][2];
#pragma unroll
    for (int m = 0; m < 2; ++m)
#pragma unroll
        for (int u = 0; u < 2; ++u)
#pragma unroll
            for (int v = 0; v < 2; ++v) {
                const float val = acc[m][u][v] + bz[m];
                const f16 h_ = (f16)val;
                hi[m][u][v] = h_;
                lo[m][u][v] = (f16)(val - (float)h_);
            }
#pragma unroll
    for (int u = 0; u < 2; ++u)
#pragma unroll
        for (int v = 0; v < 2; ++v) {
            const int s = s0 + 2 * q + v + 32 * u;
            const int w = (b * S_ + s) * 64 + (d0 >> 1) + p;   // pack over d-pair
            epA_h[w] = pack2(hi[0][u][v], hi[1][u][v]);
            epA_l[w] = pack2(lo[0][u][v], lo[1][u][v]);
        }
#pragma unroll
    for (int m = 0; m < 2; ++m)
#pragma unroll
        for (int u = 0; u < 2; ++u) {
            const int d = d0 + 2 * p + m;
            const int w = (b * D_ + d) * 64 + (s0 >> 1) + q + 16 * u; // pack over s-pair
            epT_h[w] = pack2(hi[m][u][0], hi[m][u][1]);
        }
}

// ---------------------------------------------------------------------------
// K2: one WG per (b, 64-col n-tile). MFMA everywhere.
//  phase1: sc[128 s][64 j] = ep x h   (f16 hi/lo split, 3 mfma chains)
//  softmax over s
//  phase2: c[128 d][64 j] = epT x beta (single f16)
// LDS: reg1 34816B (hT hi/lo f16 -> sc f32 -> cbuf f32), reg2 17408B
//      (h-transpose bounce -> betaT f16), red 2KB. 54272B -> 3 WG/CU.
// ---------------------------------------------------------------------------
__global__ __launch_bounds__(256) void k2_attn(
    const float* __restrict__ h, const f16* __restrict__ epA_h,
    const f16* __restrict__ epA_l, const f16* __restrict__ epT_h,
    float* __restrict__ out)
{
    __shared__ __align__(16) unsigned char reg1[34816];
    __shared__ __align__(16) unsigned char reg2[17408];
    __shared__ float red1[4][64];
    __shared__ float red2[4][64];

    f16*   hT_h = (f16*)reg1;                 // [64][136] halves
    f16*   hT_l = (f16*)(reg1 + 17408);
    float* sc   = (float*)reg1;               // [128][68] floats (after phase1)
    float* cb   = (float*)reg1;               // [128][68] floats (phase2 out)
    f16*   bT   = (f16*)reg2;                 // [64][136] halves (beta^T)
    float* stg  = (float*)reg2;               // [32][68] floats (bounce)

    const int t = threadIdx.x;
    const int b  = blockIdx.x >> 6;
    const int n0 = (blockIdx.x & 63) << 6;
    const int wid = t >> 6, lane = t & 63;
    const int l16 = lane & 15, quad = lane >> 4;

    // ---- stage h[b][:, n0:n0+64] -> hT hi/lo (transposed, f16 split) ----
    const int jj = t & 63;
    const int dg = (t >> 6) << 3;     // 8 d's per thread per chunk
    unsigned* dstH = (unsigned*)hT_h;
    unsigned* dstL = (unsigned*)hT_l;
    for (int ch = 0; ch < 4; ++ch) {
#pragma unroll
        for (int r = 0; r < 2; ++r) {
            const int lin = r * 256 + t;
            const int dd = lin >> 4, m4 = (lin & 15) << 2;
            *(float4*)(stg + dd * 68 + m4) =
                *(const float4*)(h + (b * D_ + ch * 32 + dd) * N_ + n0 + m4);
        }
        __syncthreads();
        f16 vh[8], vl[8];
#pragma unroll
        for (int x = 0; x < 8; ++x) {
            const float v = stg[(dg + x) * 68 + jj];
            vh[x] = (f16)v;
            vl[x] = (f16)(v - (float)vh[x]);
        }
        const int base = jj * 68 + (ch << 4) + (dg >> 1);
#pragma unroll
        for (int y = 0; y < 4; ++y) {
            dstH[base + y] = pack2(vh[2 * y], vh[2 * y + 1]);
            dstL[base + y] = pack2(vl[2 * y], vl[2 * y + 1]);
        }
        __syncthreads();
    }

    // ---- phase 1: scores, f16 hi/lo split (3 mfma chains) ----
    const int sb = wid << 5;
    f32x4 acc[2][4];
#pragma unroll
    for (int mt = 0; mt < 2; ++mt)
#pragma unroll
        for (int nt = 0; nt < 4; ++nt) acc[mt][nt] = (f32x4)0.f;

    const f16* Ah = epA_h + (b * S_ + sb + l16) * D_ + quad * 8;
    const f16* Al = epA_l + (b * S_ + sb + l16) * D_ + quad * 8;
#pragma unroll
    for (int kk = 0; kk < 4; ++kk) {
        const int dc = kk << 5;
        f16x8 bh[4], bl[4];
#pragma unroll
        for (int nt = 0; nt < 4; ++nt) {
            const int idx = ((nt << 4) + l16) * 136 + dc + quad * 8;
            bh[nt] = *(const f16x8*)(hT_h + idx);
            bl[nt] = *(const f16x8*)(hT_l + idx);
        }
#pragma unroll
        for (int mt = 0; mt < 2; ++mt) {
            const f16x8 ah = *(const f16x8*)(Ah + mt * 16 * D_ + dc);
            const f16x8 al = *(const f16x8*)(Al + mt * 16 * D_ + dc);
#pragma unroll
            for (int nt = 0; nt < 4; ++nt) {
                acc[mt][nt] = mfma16(ah, bh[nt], acc[mt][nt]);
                acc[mt][nt] = mfma16(ah, bl[nt], acc[mt][nt]);
                acc[mt][nt] = mfma16(al, bh[nt], acc[mt][nt]);
            }
        }
    }
    __syncthreads();                     // all waves done reading hT
#pragma unroll
    for (int mt = 0; mt < 2; ++mt)
#pragma unroll
        for (int nt = 0; nt < 4; ++nt)
#pragma unroll
            for (int r = 0; r < 4; ++r)
                sc[(sb + mt * 16 + quad * 4 + r) * 68 + (nt << 4) + l16] =
                    acc[mt][nt][r];
    __syncthreads();

    // ---- softmax over s, write beta^T f16 ----
    const int pj = t & 63, pp = t >> 6;
    float ev[32];
    float mx = -1e30f;
#pragma unroll
    for (int ss = 0; ss < 32; ++ss) {
        ev[ss] = sc[(pp * 32 + ss) * 68 + pj];
        mx = fmaxf(mx, ev[ss]);
    }
    red1[pp][pj] = mx;
    __syncthreads();
    mx = fmaxf(fmaxf(red1[0][pj], red1[1][pj]),
               fmaxf(red1[2][pj], red1[3][pj]));
    float sm = 0.f;
#pragma unroll
    for (int ss = 0; ss < 32; ++ss) {
        ev[ss] = expf(ev[ss] - mx);
        sm += ev[ss];
    }
    red2[pp][pj] = sm;
    __syncthreads();
    sm = red2[0][pj] + red2[1][pj] + red2[2][pj] + red2[3][pj];
    const float inv = 1.f / sm;
    unsigned* bTw = (unsigned*)bT;
    const int bbase = pj * 68 + pp * 16;
#pragma unroll
    for (int k = 0; k < 16; ++k)
        bTw[bbase + k] = pack2((f16)(ev[2 * k] * inv), (f16)(ev[2 * k + 1] * inv));
    __syncthreads();

    // ---- phase 2: c = epT x beta (single f16) ----
    const int db = wid << 5;
    f32x4 a2[2][4];
#pragma unroll
    for (int mt = 0; mt < 2; ++mt)
#pragma unroll
        for (int nt = 0; nt < 4; ++nt) a2[mt][nt] = (f32x4)0.f;

    const f16* At = epT_h + (b * D_ + db + l16) * S_ + quad * 8;
#pragma unroll
    for (int kk = 0; kk < 4; ++kk) {
        const int scb = kk << 5;
        f16x8 bb[4];
#pragma unroll
        for (int nt = 0; nt < 4; ++nt)
            bb[nt] = *(const f16x8*)(bT + ((nt << 4) + l16) * 136 + scb + quad * 8);
#pragma unroll
        for (int mt = 0; mt < 2; ++mt) {
            const f16x8 av = *(const f16x8*)(At + mt * 16 * S_ + scb);
#pragma unroll
            for (int nt = 0; nt < 4; ++nt)
                a2[mt][nt] = mfma16(av, bb[nt], a2[mt][nt]);
        }
    }
    // region1 (cb) is dead for all waves (sc fully consumed pre-barrier) -> no
    // barrier needed before writing own tiles.
#pragma unroll
    for (int mt = 0; mt < 2; ++mt)
#pragma unroll
        for (int nt = 0; nt < 4; ++nt)
#pragma unroll
            for (int r = 0; r < 4; ++r)
                cb[(db + mt * 16 + quad * 4 + r) * 68 + (nt << 4) + l16] =
                    a2[mt][nt][r];
    __syncthreads();

    // ---- coalesced float4 store ----
#pragma unroll
    for (int r = 0; r < 8; ++r) {
        const int lin = r * 256 + t;
        const int row = lin >> 4, c4 = (lin & 15) << 2;
        *(float4*)(out + (b * D_ + row) * N_ + n0 + c4) =
            *(float4*)(cb + row * 68 + c4);
    }
}

extern "C" void kernel_launch(void* const* d_in, const int* in_sizes, int n_in,
                              void* d_out, int out_size, void* d_ws, size_t ws_size,
                              hipStream_t stream) {
    const float* e    = (const float*)d_in[0];
    const float* h    = (const float*)d_in[1];
    const float* W    = (const float*)d_in[2];
    const float* bias = (const float*)d_in[3];
    float* out = (float*)d_out;

    unsigned* epA_h = (unsigned*)d_ws;                  // 2 MB
    unsigned* epA_l = epA_h + (B_ * S_ * D_ / 2);       // 2 MB
    unsigned* epT_h = epA_l + (B_ * S_ * D_ / 2);       // 2 MB

    hipLaunchKernelGGL(k1_ep, dim3(B_ * 8), dim3(256), 0, stream,
                       e, W, bias, epA_h, epA_l, epT_h);
    hipLaunchKernelGGL(k2_attn, dim3(B_ * 64), dim3(256), 0, stream,
                       h, (const f16*)epA_h, (const f16*)epA_l,
                       (const f16*)epT_h, out);
}